// Round 3
// baseline (2561.288 us; speedup 1.0000x reference)
//
#include <hip/hip_runtime.h>
#include <hip/hip_bf16.h>
#include <stdint.h>

typedef unsigned short u16;
typedef unsigned int u32;
typedef short short8 __attribute__((ext_vector_type(8)));
typedef float f32x4 __attribute__((ext_vector_type(4)));

__device__ __forceinline__ float bl(u32 x){ return __uint_as_float(x<<16); }
__device__ __forceinline__ float bh(u32 x){ return __uint_as_float(x & 0xffff0000u); }
__device__ __forceinline__ float b2f(u16 x){ return __uint_as_float(((u32)x)<<16); }
__device__ __forceinline__ u16 f2b(float f){
  u32 u = __float_as_uint(f);
  u32 r = (u + 0x7fffu + ((u>>16)&1u)) >> 16;
  return (u16)r;
}
__device__ __forceinline__ u32 pk2(float a, float b){ return (u32)f2b(a) | ((u32)f2b(b)<<16); }
__device__ __forceinline__ float tanh_f(float x){ return 1.f - 2.f/(__expf(2.f*x)+1.f); }
__device__ __forceinline__ float sigm(float x){ return 1.f/(1.f+__expf(-x)); }
__device__ __forceinline__ float gelu_t(float x){
  float u = 0.7978845608028654f*(x + 0.044715f*x*x*x);
  return 0.5f*x*(1.f + tanh_f(u));
}
// dtype-adaptive input load: f==1 -> f32, f==0 -> bf16
__device__ __forceinline__ float ldin(const void* p, size_t i, int f){
  return f ? ((const float*)p)[i] : b2f(((const u16*)p)[i]);
}

// ---------------- dtype probe: flags[15] = 1 if inputs are f32 ----------------
__global__ void probe_dtype(const u16* __restrict__ x, int* __restrict__ flags){
  __shared__ int cnt;
  if (threadIdx.x==0) cnt = 0;
  __syncthreads();
  int plaus = 0;
  #pragma unroll
  for (int j=0;j<4;++j){
    u16 v = x[(threadIdx.x*4+j)*2];   // even u16 indices: low half of f32 words
    int e = (v>>7)&255;
    if (v==0 || (e>=117 && e<=130)) plaus++;
  }
  atomicAdd(&cnt, plaus);
  __syncthreads();
  if (threadIdx.x==0) flags[15] = (cnt < 512) ? 1 : 0;
}

// ---------------- canary NaN checks ----------------
__global__ void checkb(const u16* __restrict__ b, int* __restrict__ flags, int slot){
  size_t i = ((size_t)blockIdx.x*256 + threadIdx.x)*4;
  bool bad = false;
  #pragma unroll
  for (int j=0;j<4;++j){ u16 v = b[i+j]; if ((v&0x7fff) >= 0x7f80) bad = true; }
  if (bad) atomicOr(&flags[slot], 1);
}
__global__ void checkf(const float* __restrict__ b, int* __restrict__ flags, int slot){
  size_t i = ((size_t)blockIdx.x*256 + threadIdx.x)*4;
  float4 v = *(const float4*)(b+i);
  bool bad = !(fabsf(v.x)<1e30f) || !(fabsf(v.y)<1e30f) || !(fabsf(v.z)<1e30f) || !(fabsf(v.w)<1e30f);
  if (bad) atomicOr(&flags[slot], 1);
}

// ---------------- host-guard constant write (bf16 pattern, safe either dtype) ----------------
__global__ void write_const16(u16* __restrict__ out, u32 pat){
  size_t i4 = ((size_t)blockIdx.x*256 + threadIdx.x)*4;
  uint2 o; o.x = pat; o.y = pat;
  *(uint2*)(out + i4) = o;
}

// ---------------- transpose [R,C] -> bf16 [C,R], dtype-adaptive ----------------
__global__ void transpose_any(const void* __restrict__ in, u16* __restrict__ out, int R, int C,
                              const int* __restrict__ flags){
  int f = flags[15];
  __shared__ u16 t[32][33];
  int c0 = blockIdx.x*32, r0 = blockIdx.y*32;
  int tx = threadIdx.x, ty = threadIdx.y;   // 32 x 8
  #pragma unroll
  for (int i=0;i<4;++i){
    size_t idx = (size_t)(r0+ty+i*8)*C + c0+tx;
    t[ty+i*8][tx] = f ? f2b(((const float*)in)[idx]) : ((const u16*)in)[idx];
  }
  __syncthreads();
  #pragma unroll
  for (int i=0;i<4;++i) out[(size_t)(c0+ty+i*8)*R + r0+tx] = t[tx][ty+i*8];
}

// ---------------- silu on c ----------------
__global__ void silu_in(const void* __restrict__ c, float* __restrict__ cs,
                        const int* __restrict__ flags){
  int f = flags[15];
  int i = blockIdx.x*256 + threadIdx.x;
  float v = ldin(c, i, f);
  cs[i] = v * sigm(v);
}

// ---------------- small mod GEMM: out[32,Nw] = cs@W + b ----------------
__global__ void mod_gemm(const float* __restrict__ cs, const void* __restrict__ W,
                         const void* __restrict__ b, float* __restrict__ out, int Nw,
                         const int* __restrict__ flags){
  int f = flags[15];
  int j = blockIdx.x*256 + threadIdx.x;
  int row = blockIdx.y;
  const float* cp = cs + (size_t)row*1024;
  float acc = ldin(b, j, f);
  for (int k=0;k<1024;++k) acc += cp[k]*ldin(W, (size_t)k*Nw + j, f);
  out[(size_t)row*Nw + j] = acc;
}

// ---------------- bias convert to bf16 ----------------
__global__ void bias_cvt(const void* __restrict__ src, u16* __restrict__ dst,
                         const int* __restrict__ flags){
  int f = flags[15];
  int i = blockIdx.x*256 + threadIdx.x;
  dst[i] = f2b(ldin(src, i, f));
}
__global__ void bihh_cvt(const void* __restrict__ a, const void* __restrict__ b,
                         u16* __restrict__ dst, const int* __restrict__ flags){
  int f = flags[15];
  int i = blockIdx.x*256 + threadIdx.x;
  dst[i] = f2b(ldin(a, i, f) + ldin(b, i, f));
}

// ---------------- x -> f32 workspace ----------------
__global__ void cvt_in(const void* __restrict__ x, float* __restrict__ out,
                       const int* __restrict__ flags){
  int f = flags[15];
  size_t i4 = ((size_t)blockIdx.x*256 + threadIdx.x)*4;
  if (f){
    *(float4*)(out + i4) = *(const float4*)((const float*)x + i4);
  } else {
    uint2 u = *(const uint2*)((const u16*)x + i4);
    float4 v; v.x=bl(u.x); v.y=bh(u.x); v.z=bl(u.y); v.w=bh(u.y);
    *(float4*)(out + i4) = v;
  }
}

// ---------------- LayerNorm + modulate -> bf16 (optional temporal permute) ----------------
__global__ __launch_bounds__(256)
void ln_mod(const float* __restrict__ xf, const float* __restrict__ mod, int stride,
            int shift_off, int scale_off, u16* __restrict__ out, int perm){
  int tok = blockIdx.x;
  int tid = threadIdx.x;
  const float* xp = xf + (size_t)tok*1024;
  float4 v = *(const float4*)(xp + tid*4);
  __shared__ float r1[256];
  __shared__ float r2[256];
  r1[tid] = v.x+v.y+v.z+v.w;
  r2[tid] = v.x*v.x+v.y*v.y+v.z*v.z+v.w*v.w;
  __syncthreads();
  for (int off=128; off>0; off>>=1){
    if (tid < off){ r1[tid] += r1[tid+off]; r2[tid] += r2[tid+off]; }
    __syncthreads();
  }
  float mean = r1[0]*(1.f/1024.f);
  float var  = r2[0]*(1.f/1024.f) - mean*mean;
  float rstd = rsqrtf(fmaxf(var, 0.f) + 1e-6f);
  int bt = tok >> 8;
  const float* mr = mod + (size_t)bt*stride;
  int d = tid*4;
  float4 sh = *(const float4*)(mr + shift_off + d);
  float4 sc = *(const float4*)(mr + scale_off + d);
  size_t otok;
  if (perm){ int b=tok>>12, t=(tok>>8)&15, ss=tok&255; otok = ((size_t)(b*256+ss)*16 + t); }
  else otok = tok;
  float y0 = (v.x-mean)*rstd*(1.f+sc.x)+sh.x;
  float y1 = (v.y-mean)*rstd*(1.f+sc.y)+sh.y;
  float y2 = (v.z-mean)*rstd*(1.f+sc.z)+sh.z;
  float y3 = (v.w-mean)*rstd*(1.f+sc.w)+sh.w;
  uint2 ub; ub.x = pk2(y0,y1); ub.y = pk2(y2,y3);
  *(uint2*)(out + otok*1024 + d) = ub;
}

// ---------------- gate + residual add into xf ----------------
__global__ void gate_add(float* __restrict__ xf, const u16* __restrict__ o,
                         const float* __restrict__ mod, int stride, int goff, int perm){
  size_t i4 = ((size_t)blockIdx.x*256 + threadIdx.x)*4;
  int tok = (int)(i4 >> 10);
  int d   = (int)(i4 & 1023);
  int bt  = tok >> 8;
  size_t stok;
  if (perm){ int b=tok>>12, t=(tok>>8)&15, ss=tok&255; stok = ((size_t)(b*256+ss)*16 + t); }
  else stok = tok;
  uint2 u = *(const uint2*)(o + stok*1024 + d);
  float4 g = *(const float4*)(mod + (size_t)bt*stride + goff + d);
  float4 x = *(float4*)(xf + i4);
  x.x += bl(u.x)*g.x; x.y += bh(u.x)*g.y; x.z += bl(u.y)*g.z; x.w += bh(u.y)*g.w;
  *(float4*)(xf + i4) = x;
}

// ---------------- MFMA GEMM: C[M,N] = A[M,K] * BT[N,K]^T, epilogues ----------------
// KIND: 0 plain->bf16, 1 +bias->bf16, 2 +bias gelu->bf16, 3 +addend(bf16)->f32
template<int KIND>
__global__ __launch_bounds__(256, 2)
void gemm_nt(const u16* __restrict__ A, const u16* __restrict__ BT,
             u16* __restrict__ outb, float* __restrict__ outf,
             const u16* __restrict__ bias1,
             const u16* __restrict__ addend, long astr,
             int M, int N, int K){
  __shared__ u16 As[128*40];
  __shared__ u16 Bs[128*40];
  const int tid  = threadIdx.x;
  const int wid  = tid >> 6, lane = tid & 63;
  const int l16  = lane & 15, quad = lane >> 4;
  const int wm   = wid >> 1,  wn   = wid & 1;
  const int m0   = blockIdx.y * 128, n0 = blockIdx.x * 128;
  f32x4 acc[4][4];
  #pragma unroll
  for (int i=0;i<4;++i)
    #pragma unroll
    for (int j=0;j<4;++j) acc[i][j] = (f32x4){0.f,0.f,0.f,0.f};

  for (int kt = 0; kt < K; kt += 32){
    #pragma unroll
    for (int r = 0; r < 2; ++r){
      int flat = tid + r*256;
      int row  = flat >> 2;
      int c8   = (flat & 3) << 3;
      *(uint4*)&As[row*40 + c8] = *(const uint4*)&A [(size_t)(m0+row)*K + kt + c8];
      *(uint4*)&Bs[row*40 + c8] = *(const uint4*)&BT[(size_t)(n0+row)*K + kt + c8];
    }
    __syncthreads();
    short8 af[4], bfr[4];
    #pragma unroll
    for (int i=0;i<4;++i) af[i]  = *(const short8*)&As[(wm*64+i*16+l16)*40 + quad*8];
    #pragma unroll
    for (int j=0;j<4;++j) bfr[j] = *(const short8*)&Bs[(wn*64+j*16+l16)*40 + quad*8];
    #pragma unroll
    for (int i=0;i<4;++i)
      #pragma unroll
      for (int j=0;j<4;++j)
        acc[i][j] = __builtin_amdgcn_mfma_f32_16x16x32_bf16(af[i], bfr[j], acc[i][j], 0,0,0);
    __syncthreads();
  }
  #pragma unroll
  for (int j=0;j<4;++j){
    int col = n0 + wn*64 + j*16 + l16;
    float bias = 0.f;
    if (KIND==1 || KIND==2) bias = b2f(bias1[col]);
    #pragma unroll
    for (int i=0;i<4;++i){
      #pragma unroll
      for (int r=0;r<4;++r){
        int row = m0 + wm*64 + i*16 + quad*4 + r;
        float v = acc[i][j][r];
        if (KIND==1||KIND==2) v += bias;
        if (KIND==2) v = gelu_t(v);
        if (KIND==3){
          v += b2f(addend[(size_t)row*astr + col]);
          outf[(size_t)row*N + col] = v;
        } else {
          outb[(size_t)row*N + col] = f2b(v);
        }
      }
    }
  }
}

// ---------------- spatial attention ----------------
__global__ __launch_bounds__(256, 2)
void attn_spatial(const u16* __restrict__ qkv, u16* __restrict__ out){
  int h = blockIdx.x, n = blockIdx.y;
  int q = threadIdx.x;
  __shared__ float Ks[64*64];
  __shared__ float Vs[64*64];
  float qr[64];
  const u16* qp = qkv + ((size_t)(n*256+q)*3072 + h*64);
  #pragma unroll
  for (int i=0;i<8;++i){
    uint4 u = *(const uint4*)(qp + i*8);
    qr[i*8+0]=bl(u.x)*0.125f; qr[i*8+1]=bh(u.x)*0.125f;
    qr[i*8+2]=bl(u.y)*0.125f; qr[i*8+3]=bh(u.y)*0.125f;
    qr[i*8+4]=bl(u.z)*0.125f; qr[i*8+5]=bh(u.z)*0.125f;
    qr[i*8+6]=bl(u.w)*0.125f; qr[i*8+7]=bh(u.w)*0.125f;
  }
  float m=-30000.f, l=0.f, acc[64];
  #pragma unroll
  for (int d=0;d<64;++d) acc[d]=0.f;
  int srow = q>>2, sc0 = (q&3)*16;
  for (int kt=0; kt<256; kt+=64){
    const u16* kp = qkv + ((size_t)(n*256+kt+srow)*3072 + 1024 + h*64 + sc0);
    #pragma unroll
    for (int i=0;i<2;++i){
      uint4 u = *(const uint4*)(kp + i*8);
      float* dk = &Ks[srow*64 + sc0 + i*8];
      dk[0]=bl(u.x); dk[1]=bh(u.x); dk[2]=bl(u.y); dk[3]=bh(u.y);
      dk[4]=bl(u.z); dk[5]=bh(u.z); dk[6]=bl(u.w); dk[7]=bh(u.w);
      uint4 w = *(const uint4*)(kp + 1024 + i*8);
      float* dv = &Vs[srow*64 + sc0 + i*8];
      dv[0]=bl(w.x); dv[1]=bh(w.x); dv[2]=bl(w.y); dv[3]=bh(w.y);
      dv[4]=bl(w.z); dv[5]=bh(w.z); dv[6]=bl(w.w); dv[7]=bh(w.w);
    }
    __syncthreads();
    for (int kv=0; kv<64; ++kv){
      const float4* kr = (const float4*)&Ks[kv*64];
      float s = 0.f;
      #pragma unroll
      for (int d=0; d<16; ++d){
        float4 kk = kr[d];
        s += qr[d*4+0]*kk.x + qr[d*4+1]*kk.y + qr[d*4+2]*kk.z + qr[d*4+3]*kk.w;
      }
      float mnew  = fmaxf(m, s);
      float scale = __expf(m - mnew);
      float p     = __expf(s - mnew);
      l = l*scale + p;
      const float4* vr = (const float4*)&Vs[kv*64];
      #pragma unroll
      for (int d=0;d<16;++d){
        float4 vv = vr[d];
        acc[d*4+0] = acc[d*4+0]*scale + p*vv.x;
        acc[d*4+1] = acc[d*4+1]*scale + p*vv.y;
        acc[d*4+2] = acc[d*4+2]*scale + p*vv.z;
        acc[d*4+3] = acc[d*4+3]*scale + p*vv.w;
      }
      m = mnew;
    }
    __syncthreads();
  }
  float rl = 1.f/l;
  u16* op = out + ((size_t)(n*256+q)*1024 + h*64);
  #pragma unroll
  for (int i=0;i<8;++i){
    uint4 ub;
    ub.x = pk2(acc[i*8+0]*rl, acc[i*8+1]*rl);
    ub.y = pk2(acc[i*8+2]*rl, acc[i*8+3]*rl);
    ub.z = pk2(acc[i*8+4]*rl, acc[i*8+5]*rl);
    ub.w = pk2(acc[i*8+6]*rl, acc[i*8+7]*rl);
    *(uint4*)(op + i*8) = ub;
  }
}

// ---------------- temporal causal attention ----------------
__global__ __launch_bounds__(256, 2)
void attn_temporal(const u16* __restrict__ qkv, u16* __restrict__ out){
  int n = blockIdx.x;
  int tid = threadIdx.x;
  int h = tid>>4, q = tid&15;
  __shared__ u16 KV[16*2048];
  #pragma unroll
  for (int i=0;i<16;++i){
    int u4i = tid + i*256;
    int e = u4i*8;
    int t = e>>11, cc = e&2047;
    *(uint4*)&KV[t*2048 + cc] = *(const uint4*)(qkv + ((size_t)(n*16+t)*3072 + 1024 + cc));
  }
  __syncthreads();
  float qr[64];
  const u16* qp = qkv + ((size_t)(n*16+q)*3072 + h*64);
  #pragma unroll
  for (int i=0;i<8;++i){
    uint4 u = *(const uint4*)(qp + i*8);
    qr[i*8+0]=bl(u.x)*0.125f; qr[i*8+1]=bh(u.x)*0.125f;
    qr[i*8+2]=bl(u.y)*0.125f; qr[i*8+3]=bh(u.y)*0.125f;
    qr[i*8+4]=bl(u.z)*0.125f; qr[i*8+5]=bh(u.z)*0.125f;
    qr[i*8+6]=bl(u.w)*0.125f; qr[i*8+7]=bh(u.w)*0.125f;
  }
  float sc[16]; float m = -30000.f;
  #pragma unroll
  for (int kv=0; kv<16; ++kv){
    const uint4* kr = (const uint4*)&KV[kv*2048 + h*64];
    float s = 0.f;
    #pragma unroll
    for (int i=0;i<8;++i){
      uint4 u = kr[i];
      s += qr[i*8+0]*bl(u.x) + qr[i*8+1]*bh(u.x) + qr[i*8+2]*bl(u.y) + qr[i*8+3]*bh(u.y)
         + qr[i*8+4]*bl(u.z) + qr[i*8+5]*bh(u.z) + qr[i*8+6]*bl(u.w) + qr[i*8+7]*bh(u.w);
    }
    s = (kv<=q) ? s : -30000.f;
    sc[kv]=s; m = fmaxf(m,s);
  }
  float l=0.f, acc[64];
  #pragma unroll
  for (int d=0;d<64;++d) acc[d]=0.f;
  #pragma unroll
  for (int kv=0; kv<16; ++kv){
    float p = __expf(sc[kv]-m);
    l += p;
    const uint4* vr = (const uint4*)&KV[kv*2048 + 1024 + h*64];
    #pragma unroll
    for (int i=0;i<8;++i){
      uint4 u = vr[i];
      acc[i*8+0]+=p*bl(u.x); acc[i*8+1]+=p*bh(u.x); acc[i*8+2]+=p*bl(u.y); acc[i*8+3]+=p*bh(u.y);
      acc[i*8+4]+=p*bl(u.z); acc[i*8+5]+=p*bh(u.z); acc[i*8+6]+=p*bl(u.w); acc[i*8+7]+=p*bh(u.w);
    }
  }
  float rl = 1.f/l;
  u16* op = out + ((size_t)(n*16+q)*1024 + h*64);
  #pragma unroll
  for (int i=0;i<8;++i){
    uint4 ub;
    ub.x = pk2(acc[i*8+0]*rl, acc[i*8+1]*rl);
    ub.y = pk2(acc[i*8+2]*rl, acc[i*8+3]*rl);
    ub.z = pk2(acc[i*8+4]*rl, acc[i*8+5]*rl);
    ub.w = pk2(acc[i*8+6]*rl, acc[i*8+7]*rl);
    *(uint4*)(op + i*8) = ub;
  }
}

// ---------------- LSTM pointwise ----------------
__global__ void lstm_point(const float* __restrict__ g4, float* __restrict__ cst,
                           u16* __restrict__ hst, u16* __restrict__ hout, int t){
  size_t i4 = ((size_t)blockIdx.x*256 + threadIdx.x)*4;
  int nn = (int)(i4 >> 10);
  int d  = (int)(i4 & 1023);
  const float* g = g4 + (size_t)nn*4096 + d;
  float4 gi = *(const float4*)(g);
  float4 gf = *(const float4*)(g+1024);
  float4 gg = *(const float4*)(g+2048);
  float4 go = *(const float4*)(g+3072);
  float4 c = *(float4*)(cst + i4);
  c.x = sigm(gf.x)*c.x + sigm(gi.x)*tanh_f(gg.x);
  c.y = sigm(gf.y)*c.y + sigm(gi.y)*tanh_f(gg.y);
  c.z = sigm(gf.z)*c.z + sigm(gi.z)*tanh_f(gg.z);
  c.w = sigm(gf.w)*c.w + sigm(gi.w)*tanh_f(gg.w);
  float h0 = sigm(go.x)*tanh_f(c.x);
  float h1 = sigm(go.y)*tanh_f(c.y);
  float h2 = sigm(go.z)*tanh_f(c.z);
  float h3 = sigm(go.w)*tanh_f(c.w);
  *(float4*)(cst + i4) = c;
  uint2 hb; hb.x = pk2(h0,h1); hb.y = pk2(h2,h3);
  *(uint2*)(hst + i4) = hb;
  *(uint2*)(hout + ((size_t)nn*16 + t)*1024 + d) = hb;
}

// ---------------- final: out = xf + gate(lstm_h); diag bands on canary ----------------
__device__ __forceinline__ float scrub(float v){ return (v==v && fabsf(v) < 1e30f) ? v : 208.f; }
__global__ void final_out(const float* __restrict__ xf, const u16* __restrict__ hout,
                          const float* __restrict__ rmod, void* __restrict__ outv,
                          const int* __restrict__ flags){
  int f32o = flags[15];
  int bad = -1;
  #pragma unroll
  for (int k=0;k<12;++k) if (bad<0 && flags[k]) bad = k;
  size_t i4 = ((size_t)blockIdx.x*256 + threadIdx.x)*4;
  if (bad >= 0){
    float val = (float)(16*(bad+1) + (f32o ? 512 : 0));
    if (f32o){ float4 o = {val,val,val,val}; *(float4*)((float*)outv + i4) = o; }
    else { u16 vb = f2b(val); u32 pp = (u32)vb | ((u32)vb<<16); uint2 o = {pp,pp}; *(uint2*)((u16*)outv + i4) = o; }
    return;
  }
  int tok = (int)(i4>>10), d = (int)(i4&1023);
  int bt = tok>>8;
  int b=tok>>12, t=(tok>>8)&15, ss=tok&255;
  size_t src = (((size_t)(b*256+ss)*16 + t)*1024) + d;
  uint2 u = *(const uint2*)(hout + src);
  float4 g = *(const float4*)(rmod + (size_t)bt*3072 + 2048 + d);
  float4 x = *(const float4*)(xf + i4);
  float y0 = scrub(x.x + bl(u.x)*g.x);
  float y1 = scrub(x.y + bh(u.x)*g.y);
  float y2 = scrub(x.z + bl(u.y)*g.z);
  float y3 = scrub(x.w + bh(u.y)*g.w);
  if (f32o){ float4 o = {y0,y1,y2,y3}; *(float4*)((float*)outv + i4) = o; }
  else { uint2 o; o.x = pk2(y0,y1); o.y = pk2(y2,y3); *(uint2*)((u16*)outv + i4) = o; }
}

extern "C" void kernel_launch(void* const* d_in, const int* in_sizes, int n_in,
                              void* d_out, int out_size, void* d_ws, size_t ws_size,
                              hipStream_t stream){
  (void)in_sizes;
  const void* x       = d_in[0];
  const void* c       = d_in[1];
  const void* s_ada_w = d_in[2];
  const void* s_ada_b = d_in[3];
  const void* t_ada_w = d_in[4];
  const void* t_ada_b = d_in[5];
  const void* r_ada_w = d_in[6];
  const void* r_ada_b = d_in[7];
  const void* s_qkv_w = d_in[8];
  const void* s_out_w = d_in[9];
  const void* s_out_b = d_in[10];
  const void* t_qkv_w = d_in[11];
  const void* t_out_w = d_in[12];
  const void* t_out_b = d_in[13];
  const void* s_mlp_w1= d_in[14];
  const void* s_mlp_b1= d_in[15];
  const void* s_mlp_w2= d_in[16];
  const void* s_mlp_b2= d_in[17];
  const void* t_mlp_w1= d_in[18];
  const void* t_mlp_b1= d_in[19];
  const void* t_mlp_w2= d_in[20];
  const void* t_mlp_b2= d_in[21];
  const void* w_ih    = d_in[22];
  const void* w_hh    = d_in[23];
  const void* b_ih    = d_in[24];
  const void* b_hh    = d_in[25];

  char* p = (char*)d_ws;
  auto alloc = [&](size_t sz){ void* r = (void*)p; p += (sz + 255) & ~(size_t)255; return r; };
  float* xf    = (float*)alloc(8192ull*1024*4);
  u16*   h16   = (u16*)  alloc(8192ull*1024*2);
  u16*   big   = (u16*)  alloc(8192ull*4096*2);
  u16*   o16   = (u16*)  alloc(8192ull*1024*2);
  float* gates = (float*)alloc(512ull*4096*4);
  float* cst   = (float*)alloc(512ull*1024*4);
  u16*   hst   = (u16*)  alloc(512ull*1024*2);
  float* cs    = (float*)alloc(32ull*1024*4);
  float* smod  = (float*)alloc(32ull*6144*4);
  float* tmod  = (float*)alloc(32ull*6144*4);
  float* rmod  = (float*)alloc(32ull*3072*4);
  u16*   wT    = (u16*)  alloc(4096ull*1024*2);
  u16*   whhT  = (u16*)  alloc(4096ull*1024*2);
  u16*   sob   = (u16*)  alloc(1024*2);
  u16*   tob   = (u16*)  alloc(1024*2);
  u16*   smb1  = (u16*)  alloc(4096*2);
  u16*   smb2  = (u16*)  alloc(1024*2);
  u16*   tmb1  = (u16*)  alloc(4096*2);
  u16*   tmb2  = (u16*)  alloc(1024*2);
  u16*   bihh  = (u16*)  alloc(4096*2);
  int*   flags = (int*)  alloc(64*4);
  size_t used = (size_t)(p - (char*)d_ws);

  int oblocks = (out_size + 1023) / 1024;
  if (n_in != 26){ write_const16<<<oblocks,256,0,stream>>>((u16*)d_out, 0x43C043C0u); return; } // 384
  if (used > ws_size){ write_const16<<<oblocks,256,0,stream>>>((u16*)d_out, 0x43804380u); return; } // 256

  hipMemsetAsync(flags, 0, 64*4, stream);
  probe_dtype<<<1,256,0,stream>>>((const u16*)x, flags);

  dim3 tb(32,8);
  auto T = [&](const void* in, u16* out, int R, int C){
    transpose_any<<<dim3(C/32, R/32), tb, 0, stream>>>(in, out, R, C, flags);
  };
  auto GEMM = [&](int kind, const u16* A, const u16* BT, void* out,
                  const u16* b1, const u16* add, long astr, int M, int N, int K){
    dim3 g(N/128, M/128);
    switch(kind){
      case 0: gemm_nt<0><<<g,256,0,stream>>>(A,BT,(u16*)out,nullptr,nullptr,nullptr,0,M,N,K); break;
      case 1: gemm_nt<1><<<g,256,0,stream>>>(A,BT,(u16*)out,nullptr,b1,nullptr,0,M,N,K); break;
      case 2: gemm_nt<2><<<g,256,0,stream>>>(A,BT,(u16*)out,nullptr,b1,nullptr,0,M,N,K); break;
      case 3: gemm_nt<3><<<g,256,0,stream>>>(A,BT,nullptr,(float*)out,nullptr,add,astr,M,N,K); break;
    }
  };
  auto CKB = [&](const u16* b, size_t n, int slot){ checkb<<<(int)(n/1024),256,0,stream>>>(b, flags, slot); };
  auto CKF = [&](const float* b, size_t n, int slot){ checkf<<<(int)(n/1024),256,0,stream>>>(b, flags, slot); };

  cvt_in<<<8192,256,0,stream>>>(x, xf, flags);
  silu_in<<<128,256,0,stream>>>(c, cs, flags);
  mod_gemm<<<dim3(24,32),256,0,stream>>>(cs, s_ada_w, s_ada_b, smod, 6144, flags);
  mod_gemm<<<dim3(24,32),256,0,stream>>>(cs, t_ada_w, t_ada_b, tmod, 6144, flags);
  mod_gemm<<<dim3(12,32),256,0,stream>>>(cs, r_ada_w, r_ada_b, rmod, 3072, flags);
  bias_cvt<<<4,256,0,stream>>>(s_out_b, sob, flags);
  bias_cvt<<<4,256,0,stream>>>(t_out_b, tob, flags);
  bias_cvt<<<16,256,0,stream>>>(s_mlp_b1, smb1, flags);
  bias_cvt<<<4,256,0,stream>>>(s_mlp_b2, smb2, flags);
  bias_cvt<<<16,256,0,stream>>>(t_mlp_b1, tmb1, flags);
  bias_cvt<<<4,256,0,stream>>>(t_mlp_b2, tmb2, flags);
  bihh_cvt<<<16,256,0,stream>>>(b_ih, b_hh, bihh, flags);
  CKF(xf, 8192ull*1024, 0);
  CKF(smod, 32ull*6144, 1); CKF(tmod, 32ull*6144, 1); CKF(rmod, 32ull*3072, 1);

  // ---- spatial attention
  ln_mod<<<8192,256,0,stream>>>(xf, smod, 6144, 0, 1024, h16, 0);
  CKB(h16, 8192ull*1024, 2);
  T(s_qkv_w, wT, 1024, 3072);
  GEMM(0, h16, wT, big, nullptr, nullptr, 0, 8192, 3072, 1024);
  CKB(big, 8192ull*3072, 3);
  attn_spatial<<<dim3(16,32),256,0,stream>>>(big, h16);
  CKB(h16, 8192ull*1024, 4);
  T(s_out_w, wT, 1024, 1024);
  GEMM(1, h16, wT, o16, sob, nullptr, 0, 8192, 1024, 1024);
  gate_add<<<8192,256,0,stream>>>(xf, o16, smod, 6144, 2048, 0);
  CKF(xf, 8192ull*1024, 5);
  // ---- spatial MLP
  ln_mod<<<8192,256,0,stream>>>(xf, smod, 6144, 3072, 4096, h16, 0);
  T(s_mlp_w1, wT, 1024, 4096);
  GEMM(2, h16, wT, big, smb1, nullptr, 0, 8192, 4096, 1024);
  T(s_mlp_w2, wT, 4096, 1024);
  GEMM(1, big, wT, o16, smb2, nullptr, 0, 8192, 1024, 4096);
  gate_add<<<8192,256,0,stream>>>(xf, o16, smod, 6144, 5120, 0);
  CKF(xf, 8192ull*1024, 6);
  // ---- temporal attention
  ln_mod<<<8192,256,0,stream>>>(xf, tmod, 6144, 0, 1024, h16, 1);
  T(t_qkv_w, wT, 1024, 3072);
  GEMM(0, h16, wT, big, nullptr, nullptr, 0, 8192, 3072, 1024);
  attn_temporal<<<512,256,0,stream>>>(big, h16);
  T(t_out_w, wT, 1024, 1024);
  GEMM(1, h16, wT, o16, tob, nullptr, 0, 8192, 1024, 1024);
  gate_add<<<8192,256,0,stream>>>(xf, o16, tmod, 6144, 2048, 1);
  CKF(xf, 8192ull*1024, 7);
  // ---- temporal MLP
  ln_mod<<<8192,256,0,stream>>>(xf, tmod, 6144, 3072, 4096, h16, 0);
  T(t_mlp_w1, wT, 1024, 4096);
  GEMM(2, h16, wT, big, tmb1, nullptr, 0, 8192, 4096, 1024);
  T(t_mlp_w2, wT, 4096, 1024);
  GEMM(1, big, wT, o16, tmb2, nullptr, 0, 8192, 1024, 4096);
  gate_add<<<8192,256,0,stream>>>(xf, o16, tmod, 6144, 5120, 0);
  CKF(xf, 8192ull*1024, 8);
  // ---- LSTM branch
  ln_mod<<<8192,256,0,stream>>>(xf, rmod, 3072, 0, 1024, h16, 1);
  T(w_ih, wT, 1024, 4096);
  GEMM(1, h16, wT, big, bihh, nullptr, 0, 8192, 4096, 1024);
  CKB(big, 8192ull*4096, 9);
  T(w_hh, whhT, 1024, 4096);
  hipMemsetAsync(cst, 0, 512ull*1024*4, stream);
  hipMemsetAsync(hst, 0, 512ull*1024*2, stream);
  for (int t=0; t<16; ++t){
    GEMM(3, hst, whhT, gates, nullptr, big + (size_t)t*4096, 16*4096, 512, 4096, 1024);
    lstm_point<<<512,256,0,stream>>>(gates, cst, hst, o16, t);
  }
  CKB(o16, 8192ull*1024, 10);
  final_out<<<8192,256,0,stream>>>(xf, o16, rmod, d_out, flags);
}

// Round 5
// 2000.481 us; speedup vs baseline: 1.2803x; 1.2803x over previous
//
#include <hip/hip_runtime.h>
#include <hip/hip_bf16.h>
#include <stdint.h>

typedef unsigned short u16;
typedef unsigned int u32;
typedef short short8 __attribute__((ext_vector_type(8)));
typedef float f32x4 __attribute__((ext_vector_type(4)));

__device__ __forceinline__ float bl(u32 x){ return __uint_as_float(x<<16); }
__device__ __forceinline__ float bh(u32 x){ return __uint_as_float(x & 0xffff0000u); }
__device__ __forceinline__ float b2f(u16 x){ return __uint_as_float(((u32)x)<<16); }
__device__ __forceinline__ u16 f2b(float f){
  u32 u = __float_as_uint(f);
  u32 r = (u + 0x7fffu + ((u>>16)&1u)) >> 16;
  return (u16)r;
}
__device__ __forceinline__ u32 pk2(float a, float b){ return (u32)f2b(a) | ((u32)f2b(b)<<16); }
__device__ __forceinline__ float tanh_f(float x){ return 1.f - 2.f/(__expf(2.f*x)+1.f); }
__device__ __forceinline__ float sigm(float x){ return 1.f/(1.f+__expf(-x)); }
__device__ __forceinline__ float gelu_t(float x){
  float u = 0.7978845608028654f*(x + 0.044715f*x*x*x);
  return 0.5f*x*(1.f + tanh_f(u));
}
// async global->LDS, 16B per lane; lds base must be wave-uniform
__device__ __forceinline__ void gld_lds16(const u16* g, u16* lds_base){
  __builtin_amdgcn_global_load_lds((const __attribute__((address_space(1))) void*)g,
                                   (__attribute__((address_space(3))) void*)lds_base,
                                   16, 0, 0);
}

// ---------------- transpose f32 [R,C] -> bf16 [C,R] ----------------
__global__ void transpose_f2b(const float* __restrict__ in, u16* __restrict__ out, int R, int C){
  __shared__ u16 t[32][33];
  int c0 = blockIdx.x*32, r0 = blockIdx.y*32;
  int tx = threadIdx.x, ty = threadIdx.y;   // 32 x 8
  #pragma unroll
  for (int i=0;i<4;++i) t[ty+i*8][tx] = f2b(in[(size_t)(r0+ty+i*8)*C + c0+tx]);
  __syncthreads();
  #pragma unroll
  for (int i=0;i<4;++i) out[(size_t)(c0+ty+i*8)*R + r0+tx] = t[tx][ty+i*8];
}

// ---------------- silu ----------------
__global__ void silu_k(const float* __restrict__ c, float* __restrict__ cs){
  int i = blockIdx.x*256 + threadIdx.x;
  float v = c[i];
  cs[i] = v * sigm(v);
}

// ---------------- b_ih + b_hh ----------------
__global__ void add_bias(const float* __restrict__ a, const float* __restrict__ b,
                         float* __restrict__ o){
  int i = blockIdx.x*256 + threadIdx.x;
  o[i] = a[i] + b[i];
}

// ---------------- mod GEMM: out[32,Nw] = cs@W + b (init + k-split atomic partials) ----------------
__global__ void mod_init(const float* __restrict__ b, float* __restrict__ out, int Nw){
  int j = blockIdx.x*256 + threadIdx.x;
  out[(size_t)blockIdx.y*Nw + j] = b[j];
}
__global__ __launch_bounds__(256)
void mod_part(const float* __restrict__ cs, const float* __restrict__ W,
              float* __restrict__ out, int Nw){
  int j  = blockIdx.x*256 + threadIdx.x;
  int k0 = blockIdx.y*256;
  __shared__ float csl[32*256];
  #pragma unroll
  for (int r=0;r<32;++r) csl[r*256 + threadIdx.x] = cs[(size_t)r*1024 + k0 + threadIdx.x];
  __syncthreads();
  float acc[32];
  #pragma unroll
  for (int r=0;r<32;++r) acc[r] = 0.f;
  for (int k=0;k<256;++k){
    float wv = W[(size_t)(k0+k)*Nw + j];
    #pragma unroll
    for (int r=0;r<32;++r) acc[r] += csl[r*256+k]*wv;
  }
  #pragma unroll
  for (int r=0;r<32;++r) atomicAdd(&out[(size_t)r*Nw + j], acc[r]);
}

// ---------------- LN(+mod) of input x, copy x -> xf ----------------
__global__ __launch_bounds__(256)
void ln_first(const float* __restrict__ xin, float* __restrict__ xf,
              const float* __restrict__ mod, int stride, int shift_off, int scale_off,
              u16* __restrict__ out){
  int tok = blockIdx.x, tid = threadIdx.x;
  float4 v = *(const float4*)(xin + (size_t)tok*1024 + tid*4);
  *(float4*)(xf + (size_t)tok*1024 + tid*4) = v;
  __shared__ float r1[256], r2[256];
  r1[tid] = v.x+v.y+v.z+v.w;
  r2[tid] = v.x*v.x+v.y*v.y+v.z*v.z+v.w*v.w;
  __syncthreads();
  for (int off=128; off>0; off>>=1){
    if (tid < off){ r1[tid] += r1[tid+off]; r2[tid] += r2[tid+off]; }
    __syncthreads();
  }
  float mean = r1[0]*(1.f/1024.f);
  float var  = r2[0]*(1.f/1024.f) - mean*mean;
  float rstd = rsqrtf(fmaxf(var,0.f) + 1e-6f);
  int bt = tok >> 8;
  const float* mr = mod + (size_t)bt*stride;
  int d = tid*4;
  float4 sh = *(const float4*)(mr + shift_off + d);
  float4 sc = *(const float4*)(mr + scale_off + d);
  float y0 = (v.x-mean)*rstd*(1.f+sc.x)+sh.x;
  float y1 = (v.y-mean)*rstd*(1.f+sc.y)+sh.y;
  float y2 = (v.z-mean)*rstd*(1.f+sc.z)+sh.z;
  float y3 = (v.w-mean)*rstd*(1.f+sc.w)+sh.w;
  uint2 ub; ub.x = pk2(y0,y1); ub.y = pk2(y2,y3);
  *(uint2*)(out + (size_t)tok*1024 + d) = ub;
}

// ---------------- fused: xf += gate*o ; then LN+mod of new xf -> h16 ----------------
__global__ __launch_bounds__(256)
void gate_ln(float* __restrict__ xf, const u16* __restrict__ o,
             const float* __restrict__ gmod, int gstride, int goff, int gperm,
             const float* __restrict__ lmod, int lstride, int shift_off, int scale_off,
             u16* __restrict__ out, int lperm){
  int tok = blockIdx.x, tid = threadIdx.x;
  int bt = tok >> 8;
  size_t stok = tok;
  if (gperm){ int b=tok>>12, t=(tok>>8)&15, ss=tok&255; stok = ((size_t)(b*256+ss)*16 + t); }
  int d = tid*4;
  uint2 u = *(const uint2*)(o + stok*1024 + d);
  float4 g = *(const float4*)(gmod + (size_t)bt*gstride + goff + d);
  float* xp = xf + (size_t)tok*1024 + d;
  float4 v = *(float4*)xp;
  v.x += bl(u.x)*g.x; v.y += bh(u.x)*g.y; v.z += bl(u.y)*g.z; v.w += bh(u.y)*g.w;
  *(float4*)xp = v;
  __shared__ float r1[256], r2[256];
  r1[tid] = v.x+v.y+v.z+v.w;
  r2[tid] = v.x*v.x+v.y*v.y+v.z*v.z+v.w*v.w;
  __syncthreads();
  for (int off=128; off>0; off>>=1){
    if (tid < off){ r1[tid] += r1[tid+off]; r2[tid] += r2[tid+off]; }
    __syncthreads();
  }
  float mean = r1[0]*(1.f/1024.f);
  float var  = r2[0]*(1.f/1024.f) - mean*mean;
  float rstd = rsqrtf(fmaxf(var,0.f) + 1e-6f);
  const float* mr = lmod + (size_t)bt*lstride;
  float4 sh = *(const float4*)(mr + shift_off + d);
  float4 sc = *(const float4*)(mr + scale_off + d);
  size_t otok = tok;
  if (lperm){ int b=tok>>12, t=(tok>>8)&15, ss=tok&255; otok = ((size_t)(b*256+ss)*16 + t); }
  float y0 = (v.x-mean)*rstd*(1.f+sc.x)+sh.x;
  float y1 = (v.y-mean)*rstd*(1.f+sc.y)+sh.y;
  float y2 = (v.z-mean)*rstd*(1.f+sc.z)+sh.z;
  float y3 = (v.w-mean)*rstd*(1.f+sc.w)+sh.w;
  uint2 ub; ub.x = pk2(y0,y1); ub.y = pk2(y2,y3);
  *(uint2*)(out + otok*1024 + d) = ub;
}

// ---------------- MFMA GEMM with global_load_lds staging ----------------
// KIND: 0 plain->bf16, 1 +bias(f32)->bf16, 2 +bias gelu->bf16, 3 +addend(bf16)->f32
template<int KIND>
__global__ __launch_bounds__(256, 2)
void gemm_nt(const u16* __restrict__ A, const u16* __restrict__ BT,
             u16* __restrict__ outb, float* __restrict__ outf,
             const float* __restrict__ biasf,
             const u16* __restrict__ addend, long astr,
             int M, int N, int K){
  __shared__ u16 As[128*32];
  __shared__ u16 Bs[128*32];
  const int tid  = threadIdx.x;
  const int wid  = tid >> 6, lane = tid & 63;
  const int l16  = lane & 15, quad = lane >> 4;
  const int wm   = wid >> 1,  wn   = wid & 1;
  const int m0   = blockIdx.y * 128, n0 = blockIdx.x * 128;
  f32x4 acc[4][4];
  #pragma unroll
  for (int i=0;i<4;++i)
    #pragma unroll
    for (int j=0;j<4;++j) acc[i][j] = (f32x4){0.f,0.f,0.f,0.f};

  for (int kt = 0; kt < K; kt += 32){
    __syncthreads();
    #pragma unroll
    for (int r = 0; r < 2; ++r){
      int flat = r*256 + wid*64 + lane;
      int row  = flat >> 2;          // 128 rows x 32 cols: 4 x 16B per row
      int c8   = (flat & 3) << 3;
      gld_lds16(&A [(size_t)(m0+row)*K + kt + c8], &As[(size_t)(r*256 + wid*64)*8]);
      gld_lds16(&BT[(size_t)(n0+row)*K + kt + c8], &Bs[(size_t)(r*256 + wid*64)*8]);
    }
    __syncthreads();
    short8 af[4], bfr[4];
    #pragma unroll
    for (int i=0;i<4;++i) af[i]  = *(const short8*)&As[(wm*64+i*16+l16)*32 + quad*8];
    #pragma unroll
    for (int j=0;j<4;++j) bfr[j] = *(const short8*)&Bs[(wn*64+j*16+l16)*32 + quad*8];
    #pragma unroll
    for (int i=0;i<4;++i)
      #pragma unroll
      for (int j=0;j<4;++j)
        acc[i][j] = __builtin_amdgcn_mfma_f32_16x16x32_bf16(af[i], bfr[j], acc[i][j], 0,0,0);
  }
  #pragma unroll
  for (int j=0;j<4;++j){
    int col = n0 + wn*64 + j*16 + l16;
    float bias = 0.f;
    if (KIND==1 || KIND==2) bias = biasf[col];
    #pragma unroll
    for (int i=0;i<4;++i){
      #pragma unroll
      for (int r=0;r<4;++r){
        int row = m0 + wm*64 + i*16 + quad*4 + r;
        float v = acc[i][j][r];
        if (KIND==1||KIND==2) v += bias;
        if (KIND==2) v = gelu_t(v);
        if (KIND==3){
          v += b2f(addend[(size_t)row*astr + col]);
          outf[(size_t)row*N + col] = v;
        } else {
          outb[(size_t)row*N + col] = f2b(v);
        }
      }
    }
  }
}

// ---------------- spatial attention, MFMA flash (block = (h,n), wave = 64 q rows) ----------------
__global__ __launch_bounds__(256)
void attn_spatial_mfma(const u16* __restrict__ qkv, u16* __restrict__ out){
  constexpr int PAD = 80;
  __shared__ u16 Ks[64*PAD];
  __shared__ u16 Vt[64*PAD];
  __shared__ u16 Ps[4*64*PAD];
  int h = blockIdx.x, n = blockIdx.y;
  int tid = threadIdx.x, wid = tid>>6, lane = tid&63, l16 = lane&15, quad = lane>>4;
  u16* Pw = Ps + wid*64*PAD;
  int qrow_base = n*256 + wid*64;
  short8 qf[4][2];
  #pragma unroll
  for (int i=0;i<4;++i)
    #pragma unroll
    for (int c=0;c<2;++c)
      qf[i][c] = *(const short8*)(qkv + (size_t)(qrow_base + i*16 + l16)*3072 + h*64 + c*32 + quad*8);
  f32x4 Oc[4][4];
  float mrun[4][4], lrun[4][4];
  #pragma unroll
  for (int i=0;i<4;++i)
    #pragma unroll
    for (int j=0;j<4;++j){ Oc[i][j] = (f32x4){0.f,0.f,0.f,0.f}; mrun[i][j] = -30000.f; lrun[i][j] = 0.f; }

  for (int kt=0; kt<4; ++kt){
    __syncthreads();
    #pragma unroll
    for (int r=0;r<2;++r){
      int flat = tid + r*256;
      int row = flat>>3, c8 = (flat&7)<<3;   // 64 rows x 64 cols: 8 x 16B per row
      const u16* kp = qkv + (size_t)(n*256 + kt*64 + row)*3072 + 1024 + h*64 + c8;
      *(short8*)&Ks[row*PAD + c8] = *(const short8*)kp;
      short8 vv = *(const short8*)(kp + 1024);
      #pragma unroll
      for (int j=0;j<8;++j) Vt[(c8+j)*PAD + row] = ((const u16*)&vv)[j];
    }
    __syncthreads();
    f32x4 S[4][4];
    #pragma unroll
    for (int i=0;i<4;++i)
      #pragma unroll
      for (int jt=0;jt<4;++jt) S[i][jt] = (f32x4){0.f,0.f,0.f,0.f};
    #pragma unroll
    for (int c=0;c<2;++c){
      short8 kf[4];
      #pragma unroll
      for (int jt=0;jt<4;++jt) kf[jt] = *(const short8*)&Ks[(jt*16+l16)*PAD + c*32 + quad*8];
      #pragma unroll
      for (int i=0;i<4;++i)
        #pragma unroll
        for (int jt=0;jt<4;++jt)
          S[i][jt] = __builtin_amdgcn_mfma_f32_16x16x32_bf16(qf[i][c], kf[jt], S[i][jt], 0,0,0);
    }
    #pragma unroll
    for (int i=0;i<4;++i){
      #pragma unroll
      for (int r=0;r<4;++r){
        float rm = -30000.f;
        #pragma unroll
        for (int jt=0;jt<4;++jt){ S[i][jt][r] *= 0.125f; rm = fmaxf(rm, S[i][jt][r]); }
        #pragma unroll
        for (int off=1; off<16; off<<=1) rm = fmaxf(rm, __shfl_xor(rm, off));
        float mnew  = fmaxf(mrun[i][r], rm);
        float alpha = __expf(mrun[i][r] - mnew);
        mrun[i][r] = mnew;
        float ps = 0.f;
        #pragma unroll
        for (int jt=0;jt<4;++jt){ float pv = __expf(S[i][jt][r] - mnew); S[i][jt][r] = pv; ps += pv; }
        #pragma unroll
        for (int off=1; off<16; off<<=1) ps += __shfl_xor(ps, off);
        lrun[i][r] = lrun[i][r]*alpha + ps;
        #pragma unroll
        for (int dt=0;dt<4;++dt) Oc[i][dt][r] *= alpha;
        #pragma unroll
        for (int jt=0;jt<4;++jt) Pw[(i*16+quad*4+r)*PAD + jt*16 + l16] = f2b(S[i][jt][r]);
      }
    }
    #pragma unroll
    for (int c=0;c<2;++c){
      short8 pf[4], vf[4];
      #pragma unroll
      for (int i=0;i<4;++i)  pf[i]  = *(const short8*)&Pw[(i*16+l16)*PAD + c*32 + quad*8];
      #pragma unroll
      for (int dt=0;dt<4;++dt) vf[dt] = *(const short8*)&Vt[(dt*16+l16)*PAD + c*32 + quad*8];
      #pragma unroll
      for (int i=0;i<4;++i)
        #pragma unroll
        for (int dt=0;dt<4;++dt)
          Oc[i][dt] = __builtin_amdgcn_mfma_f32_16x16x32_bf16(pf[i], vf[dt], Oc[i][dt], 0,0,0);
    }
  }
  #pragma unroll
  for (int i=0;i<4;++i)
    #pragma unroll
    for (int r=0;r<4;++r){
      float rl = 1.f/lrun[i][r];
      int tok = qrow_base + i*16 + quad*4 + r;
      #pragma unroll
      for (int dt=0;dt<4;++dt)
        out[(size_t)tok*1024 + h*64 + dt*16 + l16] = f2b(Oc[i][dt][r]*rl);
    }
}

// ---------------- temporal causal attention (verified VALU version) ----------------
__global__ __launch_bounds__(256, 2)
void attn_temporal(const u16* __restrict__ qkv, u16* __restrict__ out){
  int n = blockIdx.x;
  int tid = threadIdx.x;
  int h = tid>>4, q = tid&15;
  __shared__ u16 KV[16*2048];
  #pragma unroll
  for (int i=0;i<16;++i){
    int u4i = tid + i*256;
    int e = u4i*8;
    int t = e>>11, cc = e&2047;
    *(uint4*)&KV[t*2048 + cc] = *(const uint4*)(qkv + ((size_t)(n*16+t)*3072 + 1024 + cc));
  }
  __syncthreads();
  float qr[64];
  const u16* qp = qkv + ((size_t)(n*16+q)*3072 + h*64);
  #pragma unroll
  for (int i=0;i<8;++i){
    uint4 u = *(const uint4*)(qp + i*8);
    qr[i*8+0]=bl(u.x)*0.125f; qr[i*8+1]=bh(u.x)*0.125f;
    qr[i*8+2]=bl(u.y)*0.125f; qr[i*8+3]=bh(u.y)*0.125f;
    qr[i*8+4]=bl(u.z)*0.125f; qr[i*8+5]=bh(u.z)*0.125f;
    qr[i*8+6]=bl(u.w)*0.125f; qr[i*8+7]=bh(u.w)*0.125f;
  }
  float sc[16]; float m = -30000.f;
  #pragma unroll
  for (int kv=0; kv<16; ++kv){
    const uint4* kr = (const uint4*)&KV[kv*2048 + h*64];
    float s = 0.f;
    #pragma unroll
    for (int i=0;i<8;++i){
      uint4 u = kr[i];
      s += qr[i*8+0]*bl(u.x) + qr[i*8+1]*bh(u.x) + qr[i*8+2]*bl(u.y) + qr[i*8+3]*bh(u.y)
         + qr[i*8+4]*bl(u.z) + qr[i*8+5]*bh(u.z) + qr[i*8+6]*bl(u.w) + qr[i*8+7]*bh(u.w);
    }
    s = (kv<=q) ? s : -30000.f;
    sc[kv]=s; m = fmaxf(m,s);
  }
  float l=0.f, acc[64];
  #pragma unroll
  for (int d=0;d<64;++d) acc[d]=0.f;
  #pragma unroll
  for (int kv=0; kv<16; ++kv){
    float p = __expf(sc[kv]-m);
    l += p;
    const uint4* vr = (const uint4*)&KV[kv*2048 + 1024 + h*64];
    #pragma unroll
    for (int i=0;i<8;++i){
      uint4 u = vr[i];
      acc[i*8+0]+=p*bl(u.x); acc[i*8+1]+=p*bh(u.x); acc[i*8+2]+=p*bl(u.y); acc[i*8+3]+=p*bh(u.y);
      acc[i*8+4]+=p*bl(u.z); acc[i*8+5]+=p*bh(u.z); acc[i*8+6]+=p*bl(u.w); acc[i*8+7]+=p*bh(u.w);
    }
  }
  float rl = 1.f/l;
  u16* op = out + ((size_t)(n*16+q)*1024 + h*64);
  #pragma unroll
  for (int i=0;i<8;++i){
    uint4 ub;
    ub.x = pk2(acc[i*8+0]*rl, acc[i*8+1]*rl);
    ub.y = pk2(acc[i*8+2]*rl, acc[i*8+3]*rl);
    ub.z = pk2(acc[i*8+4]*rl, acc[i*8+5]*rl);
    ub.w = pk2(acc[i*8+6]*rl, acc[i*8+7]*rl);
    *(uint4*)(op + i*8) = ub;
  }
}

// ---------------- LSTM pointwise ----------------
__global__ void lstm_point(const float* __restrict__ g4, float* __restrict__ cst,
                           u16* __restrict__ hst, u16* __restrict__ hout, int t){
  size_t i4 = ((size_t)blockIdx.x*256 + threadIdx.x)*4;
  int nn = (int)(i4 >> 10);
  int d  = (int)(i4 & 1023);
  const float* g = g4 + (size_t)nn*4096 + d;
  float4 gi = *(const float4*)(g);
  float4 gf = *(const float4*)(g+1024);
  float4 gg = *(const float4*)(g+2048);
  float4 go = *(const float4*)(g+3072);
  float4 c = *(float4*)(cst + i4);
  c.x = sigm(gf.x)*c.x + sigm(gi.x)*tanh_f(gg.x);
  c.y = sigm(gf.y)*c.y + sigm(gi.y)*tanh_f(gg.y);
  c.z = sigm(gf.z)*c.z + sigm(gi.z)*tanh_f(gg.z);
  c.w = sigm(gf.w)*c.w + sigm(gi.w)*tanh_f(gg.w);
  float h0 = sigm(go.x)*tanh_f(c.x);
  float h1 = sigm(go.y)*tanh_f(c.y);
  float h2 = sigm(go.z)*tanh_f(c.z);
  float h3 = sigm(go.w)*tanh_f(c.w);
  *(float4*)(cst + i4) = c;
  uint2 hb; hb.x = pk2(h0,h1); hb.y = pk2(h2,h3);
  *(uint2*)(hst + i4) = hb;
  *(uint2*)(hout + ((size_t)nn*16 + t)*1024 + d) = hb;
}

// ---------------- final: out(f32) = xf + gate(lstm_h) ----------------
__global__ void final_out(const float* __restrict__ xf, const u16* __restrict__ hout,
                          const float* __restrict__ rmod, float* __restrict__ out){
  size_t i4 = ((size_t)blockIdx.x*256 + threadIdx.x)*4;
  int tok = (int)(i4>>10), d = (int)(i4&1023);
  int bt = tok>>8;
  int b=tok>>12, t=(tok>>8)&15, ss=tok&255;
  size_t src = (((size_t)(b*256+ss)*16 + t)*1024) + d;
  uint2 u = *(const uint2*)(hout + src);
  float4 g = *(const float4*)(rmod + (size_t)bt*3072 + 2048 + d);
  float4 x = *(const float4*)(xf + i4);
  float4 o;
  o.x = x.x + bl(u.x)*g.x; o.y = x.y + bh(u.x)*g.y;
  o.z = x.z + bl(u.y)*g.z; o.w = x.w + bh(u.y)*g.w;
  *(float4*)(out + i4) = o;
}

extern "C" void kernel_launch(void* const* d_in, const int* in_sizes, int n_in,
                              void* d_out, int out_size, void* d_ws, size_t ws_size,
                              hipStream_t stream){
  (void)in_sizes; (void)n_in; (void)out_size; (void)ws_size;
  const float* x       = (const float*)d_in[0];
  const float* c       = (const float*)d_in[1];
  const float* s_ada_w = (const float*)d_in[2];
  const float* s_ada_b = (const float*)d_in[3];
  const float* t_ada_w = (const float*)d_in[4];
  const float* t_ada_b = (const float*)d_in[5];
  const float* r_ada_w = (const float*)d_in[6];
  const float* r_ada_b = (const float*)d_in[7];
  const float* s_qkv_w = (const float*)d_in[8];
  const float* s_out_w = (const float*)d_in[9];
  const float* s_out_b = (const float*)d_in[10];
  const float* t_qkv_w = (const float*)d_in[11];
  const float* t_out_w = (const float*)d_in[12];
  const float* t_out_b = (const float*)d_in[13];
  const float* s_mlp_w1= (const float*)d_in[14];
  const float* s_mlp_b1= (const float*)d_in[15];
  const float* s_mlp_w2= (const float*)d_in[16];
  const float* s_mlp_b2= (const float*)d_in[17];
  const float* t_mlp_w1= (const float*)d_in[18];
  const float* t_mlp_b1= (const float*)d_in[19];
  const float* t_mlp_w2= (const float*)d_in[20];
  const float* t_mlp_b2= (const float*)d_in[21];
  const float* w_ih    = (const float*)d_in[22];
  const float* w_hh    = (const float*)d_in[23];
  const float* b_ih    = (const float*)d_in[24];
  const float* b_hh    = (const float*)d_in[25];

  char* p = (char*)d_ws;
  auto alloc = [&](size_t sz){ void* r = (void*)p; p += (sz + 255) & ~(size_t)255; return r; };
  float* xf    = (float*)alloc(8192ull*1024*4);
  u16*   h16   = (u16*)  alloc(8192ull*1024*2);
  u16*   big   = (u16*)  alloc(8192ull*4096*2);
  u16*   o16   = (u16*)  alloc(8192ull*1024*2);
  float* gates = (float*)alloc(512ull*4096*4);
  float* cst   = (float*)alloc(512ull*1024*4);
  u16*   hst   = (u16*)  alloc(512ull*1024*2);
  float* cs    = (float*)alloc(32ull*1024*4);
  float* smod  = (float*)alloc(32ull*6144*4);
  float* tmod  = (float*)alloc(32ull*6144*4);
  float* rmod  = (float*)alloc(32ull*3072*4);
  u16*   wT    = (u16*)  alloc(4096ull*1024*2);
  u16*   whhT  = (u16*)  alloc(4096ull*1024*2);
  float* bihh  = (float*)alloc(4096*4);

  dim3 tb(32,8);
  auto T = [&](const float* in, u16* out, int R, int C){
    transpose_f2b<<<dim3(C/32, R/32), tb, 0, stream>>>(in, out, R, C);
  };
  auto GEMM = [&](int kind, const u16* A, const u16* BT, void* out,
                  const float* b1, const u16* add, long astr, int M, int N, int K){
    dim3 g(N/128, M/128);
    switch(kind){
      case 0: gemm_nt<0><<<g,256,0,stream>>>(A,BT,(u16*)out,nullptr,nullptr,nullptr,0,M,N,K); break;
      case 1: gemm_nt<1><<<g,256,0,stream>>>(A,BT,(u16*)out,nullptr,b1,nullptr,0,M,N,K); break;
      case 2: gemm_nt<2><<<g,256,0,stream>>>(A,BT,(u16*)out,nullptr,b1,nullptr,0,M,N,K); break;
      case 3: gemm_nt<3><<<g,256,0,stream>>>(A,BT,nullptr,(float*)out,nullptr,add,astr,M,N,K); break;
    }
  };
  auto MOD = [&](const float* W, const float* b, float* out, int Nw){
    mod_init<<<dim3(Nw/256,32),256,0,stream>>>(b, out, Nw);
    mod_part<<<dim3(Nw/256,4),256,0,stream>>>(cs, W, out, Nw);
  };

  silu_k<<<128,256,0,stream>>>(c, cs);
  MOD(s_ada_w, s_ada_b, smod, 6144);
  MOD(t_ada_w, t_ada_b, tmod, 6144);
  MOD(r_ada_w, r_ada_b, rmod, 3072);
  add_bias<<<16,256,0,stream>>>(b_ih, b_hh, bihh);

  // ---- spatial attention
  ln_first<<<8192,256,0,stream>>>(x, xf, smod, 6144, 0, 1024, h16);
  T(s_qkv_w, wT, 1024, 3072);
  GEMM(0, h16, wT, big, nullptr, nullptr, 0, 8192, 3072, 1024);
  attn_spatial_mfma<<<dim3(16,32),256,0,stream>>>(big, h16);
  T(s_out_w, wT, 1024, 1024);
  GEMM(1, h16, wT, o16, s_out_b, nullptr, 0, 8192, 1024, 1024);
  gate_ln<<<8192,256,0,stream>>>(xf, o16, smod, 6144, 2048, 0, smod, 6144, 3072, 4096, h16, 0);
  // ---- spatial MLP
  T(s_mlp_w1, wT, 1024, 4096);
  GEMM(2, h16, wT, big, s_mlp_b1, nullptr, 0, 8192, 4096, 1024);
  T(s_mlp_w2, wT, 4096, 1024);
  GEMM(1, big, wT, o16, s_mlp_b2, nullptr, 0, 8192, 1024, 4096);
  gate_ln<<<8192,256,0,stream>>>(xf, o16, smod, 6144, 5120, 0, tmod, 6144, 0, 1024, h16, 1);
  // ---- temporal attention
  T(t_qkv_w, wT, 1024, 3072);
  GEMM(0, h16, wT, big, nullptr, nullptr, 0, 8192, 3072, 1024);
  attn_temporal<<<512,256,0,stream>>>(big, h16);
  T(t_out_w, wT, 1024, 1024);
  GEMM(1, h16, wT, o16, t_out_b, nullptr, 0, 8192, 1024, 1024);
  gate_ln<<<8192,256,0,stream>>>(xf, o16, tmod, 6144, 2048, 1, tmod, 6144, 3072, 4096, h16, 0);
  // ---- temporal MLP
  T(t_mlp_w1, wT, 1024, 4096);
  GEMM(2, h16, wT, big, t_mlp_b1, nullptr, 0, 8192, 4096, 1024);
  T(t_mlp_w2, wT, 4096, 1024);
  GEMM(1, big, wT, o16, t_mlp_b2, nullptr, 0, 8192, 1024, 4096);
  gate_ln<<<8192,256,0,stream>>>(xf, o16, tmod, 6144, 5120, 0, rmod, 3072, 0, 1024, h16, 1);
  // ---- LSTM branch
  T(w_ih, wT, 1024, 4096);
  GEMM(1, h16, wT, big, bihh, nullptr, 0, 8192, 4096, 1024);
  T(w_hh, whhT, 1024, 4096);
  hipMemsetAsync(cst, 0, 512ull*1024*4, stream);
  hipMemsetAsync(hst, 0, 512ull*1024*2, stream);
  for (int t=0; t<16; ++t){
    GEMM(3, hst, whhT, gates, nullptr, big + (size_t)t*4096, 16*4096, 512, 4096, 1024);
    lstm_point<<<512,256,0,stream>>>(gates, cst, hst, o16, t);
  }
  final_out<<<8192,256,0,stream>>>(xf, o16, rmod, (float*)d_out);
}